// Round 1
// baseline (2922.567 us; speedup 1.0000x reference)
//
#include <hip/hip_runtime.h>
#include <hip/hip_bf16.h>
#include <cstdint>

// ---------------------------------------------------------------------------
// SsLayer: outputs[2,B,T,OUT] (loc, softplus-scale) + state_out[B,NS]
// Plan:
//   ck_* : fp32 -> f16 conversions / layout prep (x, Bm^T, [C|D]^T, A scan layout)
//   gemm<256,0>: U = x @ Bm + b            (f16 MFMA, out f16 in ws)
//   scan       : s_{t+1} = tanh(u_t + s_t A)  64 WGs (1/batch), 1024 thr
//                (4 waves/SIMD). Each thread: 4 cols x 64 k-rows = 128 fdot2.
//                A 50% in VGPRs + 50% streamed from L2 each step.
//   gemm<512,1>: loc = S@C + c ; scale = softplus(S@D + d)  (fp32 out)
// ---------------------------------------------------------------------------

typedef _Float16 f16;
typedef _Float16 f16x2 __attribute__((ext_vector_type(2)));
typedef _Float16 f16x4 __attribute__((ext_vector_type(4)));
typedef _Float16 f16x8 __attribute__((ext_vector_type(8)));
typedef float    f32x4 __attribute__((ext_vector_type(4)));

#define NS 512

// ws byte offsets (total ~129.3 MB). x16 shares the S16 region: x16 is dead
// after gemm1; scan then overwrites the region with S16.
#define OFF_S16   (0ull)            // 67,108,864   (S: [B*T, 512] f16)
#define OFF_X16   (0ull)            // 33,554,432   (x16 lives here during phase 1)
#define OFF_U16   (67108864ull)     // 67,108,864   (U: [B*T, 512] f16, bias added)
#define OFF_BMT   (134217728ull)    //    262,144   (Bm^T: [512][256] f16)
#define OFF_CDT   (134479872ull)    //    524,288   ([C|D]^T: [512][512] f16)
#define OFF_APREP (135004160ull)    //    262,144   (A reg-part, per-thread packed)
#define OFF_ASTR  (135266304ull)    //    262,144   (A streamed-part)

#if defined(__has_builtin)
#  if __has_builtin(__builtin_amdgcn_fdot2)
#    define HAS_FDOT2 1
#  endif
#endif

__device__ __forceinline__ float fdot2f(unsigned a, unsigned s, float c) {
#ifdef HAS_FDOT2
  return __builtin_amdgcn_fdot2(__builtin_bit_cast(f16x2, a),
                                __builtin_bit_cast(f16x2, s), c, false);
#else
  f16x2 av = __builtin_bit_cast(f16x2, a);
  f16x2 sv = __builtin_bit_cast(f16x2, s);
  return c + (float)av[0] * (float)sv[0] + (float)av[1] * (float)sv[1];
#endif
}

__device__ __forceinline__ unsigned packh2(float a, float b) {
  f16x2 h; h[0] = (f16)a; h[1] = (f16)b;
  return __builtin_bit_cast(unsigned, h);
}

// ------------------------------ prep kernels -------------------------------

__global__ void ck_x(const float* __restrict__ xg, f16* __restrict__ x16) {
  int i = (blockIdx.x * 256 + threadIdx.x) * 4;
  float4 v = *(const float4*)(xg + i);
  f16x4 h; h[0] = (f16)v.x; h[1] = (f16)v.y; h[2] = (f16)v.z; h[3] = (f16)v.w;
  *(f16x4*)(x16 + i) = h;
}

__global__ void ck_bmt(const float* __restrict__ Bm, f16* __restrict__ BmT) {
  int g = blockIdx.x * 256 + threadIdx.x;   // 131072 = 512*256
  int n = g >> 8, k = g & 255;
  BmT[g] = (f16)Bm[k * 512 + n];            // BmT[n][k]
}

__global__ void ck_cdt(const float* __restrict__ C, const float* __restrict__ D,
                       f16* __restrict__ CDT) {
  int g = blockIdx.x * 256 + threadIdx.x;   // 262144 = 512*512
  int n = g >> 9, k = g & 511;
  float v = (n < 256) ? C[k * 256 + n] : D[k * 256 + (n - 256)];
  CDT[g] = (f16)v;                          // CDT[n][k], n<256 -> C, else D
}

// A scan layout, 1024-thread scan. Thread t: kb = t>>7 (k-block of 64 rows),
// c = t&127; its 4 output columns are j = jj*128 + c (jj=0..3).
//  Reg part   (pairs p in [0,16), k0 = kb*64 + 2p):
//     Aprep4[t*16 + q] (q = pg*4 + jj, pg = p>>2), dword e = p&3:
//     pack(A[k0][j], A[k0+1][j])
//  Stream part (pairs p in [16,32)):
//     Astr4[f*1024 + t] (f = pg2*4 + jj, pg2 = (p-16)>>2), dword e = (p-16)&3
__global__ void ck_a(const float* __restrict__ Ag, unsigned* __restrict__ Aprep,
                     unsigned* __restrict__ Astr) {
  int g = blockIdx.x * 256 + threadIdx.x;   // 131072 packed dwords total
  int kb, c, jj, p;
  unsigned* dst;
  int idx;
  if (g < 65536) {
    int t = g >> 6, r = g & 63;
    int q = r >> 2, e = r & 3;
    jj = q & 3;
    int pg = q >> 2;
    p = pg * 4 + e;
    kb = t >> 7; c = t & 127;
    dst = Aprep; idx = g;
  } else {
    int q2 = g - 65536;
    int f = q2 >> 12, rr = q2 & 4095;
    int t = rr >> 2, e = rr & 3;
    jj = f & 3;
    int pg2 = f >> 2;
    p = 16 + pg2 * 4 + e;
    kb = t >> 7; c = t & 127;
    dst = Astr; idx = q2;
  }
  int j = jj * 128 + c;
  int k0 = kb * 64 + 2 * p;
  dst[idx] = packh2(Ag[k0 * 512 + j], Ag[(k0 + 1) * 512 + j]);
}

// ------------------------------- GEMM --------------------------------------
// C[M,128-tile] = A[M,K] @ B  with B given transposed: Bt[n][k].
// Block 256 thr = 4 waves, each wave a 64x64 quadrant, 16x16x32 f16 MFMA.
// MODE 0: out f16 = val + bias0[n]   (U)
// MODE 1: n<256 -> loc = val + bias0[n] ; else scale = softplus(val + bias1[n-256])
template <int KDIM, int MODE>
__global__ __launch_bounds__(256, 2) void gemm_kernel(
    const f16* __restrict__ Ag, const f16* __restrict__ Bt,
    const float* __restrict__ bias0, const float* __restrict__ bias1,
    void* __restrict__ outp) {
  __shared__ f16 At[128 * 40];   // 32 k + 8 pad per row (bank-conflict-free b128)
  __shared__ f16 Bs[128 * 40];
  const int tid = threadIdx.x;
  const int m0 = blockIdx.y * 128;
  const int n0 = blockIdx.x * 128;
  const int w = tid >> 6, lane = tid & 63;
  const int wm = w & 1, wn = w >> 1;
  const int r = lane & 15, qd = lane >> 4;

  f32x4 zero4 = {0.f, 0.f, 0.f, 0.f};
  f32x4 acc[4][4];
#pragma unroll
  for (int mt = 0; mt < 4; ++mt)
#pragma unroll
    for (int nt = 0; nt < 4; ++nt) acc[mt][nt] = zero4;

  for (int kk = 0; kk < KDIM; kk += 32) {
#pragma unroll
    for (int s = 0; s < 2; ++s) {
      int fi = tid * 2 + s;
      int row = fi >> 2, q = fi & 3;
      float4 av = *(const float4*)(Ag + (size_t)(m0 + row) * KDIM + kk + q * 8);
      *(float4*)(At + row * 40 + q * 8) = av;
      float4 bv = *(const float4*)(Bt + (size_t)(n0 + row) * KDIM + kk + q * 8);
      *(float4*)(Bs + row * 40 + q * 8) = bv;
    }
    __syncthreads();
    f16x8 af[4], bf[4];
#pragma unroll
    for (int mt = 0; mt < 4; ++mt)
      af[mt] = *(const f16x8*)(At + (wm * 64 + mt * 16 + r) * 40 + qd * 8);
#pragma unroll
    for (int nt = 0; nt < 4; ++nt)
      bf[nt] = *(const f16x8*)(Bs + (wn * 64 + nt * 16 + r) * 40 + qd * 8);
#pragma unroll
    for (int mt = 0; mt < 4; ++mt)
#pragma unroll
      for (int nt = 0; nt < 4; ++nt)
        acc[mt][nt] = __builtin_amdgcn_mfma_f32_16x16x32_f16(af[mt], bf[nt],
                                                             acc[mt][nt], 0, 0, 0);
    __syncthreads();
  }

#pragma unroll
  for (int mt = 0; mt < 4; ++mt) {
#pragma unroll
    for (int nt = 0; nt < 4; ++nt) {
      int n = n0 + wn * 64 + nt * 16 + r;
#pragma unroll
      for (int i = 0; i < 4; ++i) {
        int m = m0 + wm * 64 + mt * 16 + qd * 4 + i;
        float v = acc[mt][nt][i];
        if (MODE == 0) {
          ((f16*)outp)[(size_t)m * NS + n] = (f16)(v + bias0[n]);
        } else {
          if (n < 256) {
            ((float*)outp)[(size_t)m * 256 + n] = v + bias0[n];
          } else {
            float z = v + bias1[n - 256];
            float sp = (z > 20.f) ? z : log1pf(__expf(z));
            ((float*)outp)[16777216ull + (size_t)m * 256 + (n - 256)] = sp;
          }
        }
      }
    }
  }
}

// ------------------------------- scan --------------------------------------
// 1024 threads = 16 waves = 4 waves/SIMD (vs old 2/SIMD): halves the serial
// fdot2 chain per thread and gives the SIMD 4-way wave interleave to hide
// LDS-broadcast latency, L2 stream latency, barrier skew and the reduce tail.
// Register budget is hard-capped at 128 (16-wave block): A is 64 dwords in
// VGPRs + 64 dwords streamed from L2 per step (L2-resident 256 KB array).

#define BCU(x) __builtin_bit_cast(unsigned, (x))

// one k-pair (s-scalar SV) against 4 columns
#define DOT4(A0, A1, A2, A3, SV)              \
  do {                                        \
    unsigned sb_ = BCU(SV);                   \
    a0 = fdot2f(BCU(A0), sb_, a0);            \
    a1 = fdot2f(BCU(A1), sb_, a1);            \
    a2 = fdot2f(BCU(A2), sb_, a2);            \
    a3 = fdot2f(BCU(A3), sb_, a3);            \
  } while (0)

// 4 k-pairs (one s-float4) against 4 columns: quads Q0..Q3 are cols 0..3
#define DOT16(Q0, Q1, Q2, Q3, S4)             \
  do {                                        \
    DOT4((Q0).x, (Q1).x, (Q2).x, (Q3).x, (S4).x); \
    DOT4((Q0).y, (Q1).y, (Q2).y, (Q3).y, (S4).y); \
    DOT4((Q0).z, (Q1).z, (Q2).z, (Q3).z, (S4).z); \
    DOT4((Q0).w, (Q1).w, (Q2).w, (Q3).w, (S4).w); \
  } while (0)

__global__ __launch_bounds__(1024, 4) void scan_kernel(
    const float4* __restrict__ Aprep4, const float4* __restrict__ Astr4,
    const f16* __restrict__ U16, f16* __restrict__ S16,
    float* __restrict__ stout) {
  __shared__ float part[4096];                 // [kb][j] partials, 16 KB
  __shared__ __align__(16) f16 sh[512];        // state as f16 (read as float4)
  const int t = threadIdx.x;
  const int b = blockIdx.x;
  const int kb = t >> 7;                       // k-block: rows kb*64 + [0,64)
  const int c = t & 127;                       // cols j = jj*128 + c

  // A register part: 64 packed dwords (16 float4) per thread, live whole kernel
  float4 areg[16];
#pragma unroll
  for (int i = 0; i < 16; ++i) areg[i] = Aprep4[t * 16 + i];

  if (t < 512) sh[t] = (f16)0.f;               // s_0 = 0
  __syncthreads();

  const float4* sp4 = (const float4*)sh;
  float ns_prev = 0.f;

#pragma unroll 1
  for (int ts = 0; ts < 1024; ++ts) {
    // opaque zero: prevents LICM from hoisting the (loop-invariant) A-stream
    // loads out of the loop, which would blow the register budget
    int zoff;
    asm volatile("s_mov_b32 %0, 0" : "=s"(zoff));
    const float4* astr = Astr4 + zoff + t;

    f16 uh = (f16)0.f;
    if (t < 512) {
      // deferred store of last step's state: drains for free at barrier 1
      if (ts) S16[(size_t)(b * 1024 + ts - 1) * 512 + t] = (f16)ns_prev;
      uh = U16[(size_t)(b * 1024 + ts) * 512 + t];   // u_t[j=t], issued early
    }

    // stream first half of the A stream part (pairs 16..23 of this thread)
    float4 g0 = astr[0 * 1024], g1 = astr[1 * 1024];
    float4 g2 = astr[2 * 1024], g3 = astr[3 * 1024];
    float4 g4 = astr[4 * 1024], g5 = astr[5 * 1024];
    float4 g6 = astr[6 * 1024], g7 = astr[7 * 1024];

    float a0 = 0.f, a1 = 0.f, a2 = 0.f, a3 = 0.f;

    // register part: k-pairs [0,16)
#pragma unroll
    for (int pg = 0; pg < 4; ++pg) {
      float4 s4 = sp4[kb * 8 + pg];            // wave-uniform broadcast
      DOT16(areg[pg * 4 + 0], areg[pg * 4 + 1],
            areg[pg * 4 + 2], areg[pg * 4 + 3], s4);
    }

    // streamed part: k-pairs [16,32)
    {
      float4 s4 = sp4[kb * 8 + 4];
      DOT16(g0, g1, g2, g3, s4);
    }
    {
      float4 s4 = sp4[kb * 8 + 5];
      DOT16(g4, g5, g6, g7, s4);
    }
    g0 = astr[8 * 1024];  g1 = astr[9 * 1024];
    g2 = astr[10 * 1024]; g3 = astr[11 * 1024];
    g4 = astr[12 * 1024]; g5 = astr[13 * 1024];
    g6 = astr[14 * 1024]; g7 = astr[15 * 1024];
    {
      float4 s4 = sp4[kb * 8 + 6];
      DOT16(g0, g1, g2, g3, s4);
    }
    {
      float4 s4 = sp4[kb * 8 + 7];
      DOT16(g4, g5, g6, g7, s4);
    }

    // partials: [kb][j], j = jj*128 + c -> lanes write consecutive dwords
    part[kb * 512 + 0 * 128 + c] = a0;
    part[kb * 512 + 1 * 128 + c] = a1;
    part[kb * 512 + 2 * 128 + c] = a2;
    part[kb * 512 + 3 * 128 + c] = a3;
    __syncthreads();

    // reduce over k-blocks for column j = t, add u, tanh (waves 8..15 idle)
    if (t < 512) {
      float sum = (float)uh;
#pragma unroll
      for (int k2 = 0; k2 < 8; ++k2) sum += part[k2 * 512 + t];
      float e = __expf(2.f * sum);
      float ns = 1.f - 2.f / (e + 1.f);        // tanh(sum)
      sh[t] = (f16)ns;                         // direct b16 write, 2-way = free
      ns_prev = ns;
      if (ts == 1022) stout[b * 512 + t] = ns; // prev_states[-1] = s_{1023}
    }
    __syncthreads();
  }

  if (t < 512) S16[(size_t)(b * 1024 + 1023) * 512 + t] = (f16)ns_prev;
}

// ------------------------------ launcher -----------------------------------

extern "C" void kernel_launch(void* const* d_in, const int* in_sizes, int n_in,
                              void* d_out, int out_size, void* d_ws, size_t ws_size,
                              hipStream_t stream) {
  (void)in_sizes; (void)n_in; (void)out_size; (void)ws_size;
  const float* xg  = (const float*)d_in[0];
  const float* Ag  = (const float*)d_in[1];
  const float* Bmg = (const float*)d_in[2];
  const float* bg  = (const float*)d_in[3];
  const float* Cg  = (const float*)d_in[4];
  const float* cg  = (const float*)d_in[5];
  const float* Dg  = (const float*)d_in[6];
  const float* dg  = (const float*)d_in[7];

  char* w = (char*)d_ws;
  f16* x16 = (f16*)(w + OFF_X16);
  f16* U16 = (f16*)(w + OFF_U16);
  f16* S16 = (f16*)(w + OFF_S16);
  f16* BmT = (f16*)(w + OFF_BMT);
  f16* CDT = (f16*)(w + OFF_CDT);
  unsigned* Aprep = (unsigned*)(w + OFF_APREP);
  unsigned* Astr  = (unsigned*)(w + OFF_ASTR);
  float* out = (float*)d_out;

  ck_x  <<<16384, 256, 0, stream>>>(xg, x16);
  ck_bmt<<<  512, 256, 0, stream>>>(Bmg, BmT);
  ck_cdt<<< 1024, 256, 0, stream>>>(Cg, Dg, CDT);
  ck_a  <<<  512, 256, 0, stream>>>(Ag, Aprep, Astr);

  // U = x @ Bm + b
  gemm_kernel<256, 0><<<dim3(4, 512), 256, 0, stream>>>(x16, BmT, bg, nullptr,
                                                        (void*)U16);
  // sequential scan (overwrites x16 region with S16)
  scan_kernel<<<64, 1024, 0, stream>>>((const float4*)Aprep, (const float4*)Astr,
                                       U16, S16, out + 33554432);
  // loc / softplus(scale) from S
  gemm_kernel<512, 1><<<dim3(4, 512), 256, 0, stream>>>(S16, CDT, cg, dg,
                                                        (void*)out);
}

// Round 4
// 2548.687 us; speedup vs baseline: 1.1467x; 1.1467x over previous
//
#include <hip/hip_runtime.h>
#include <hip/hip_bf16.h>
#include <cstdint>

// ---------------------------------------------------------------------------
// SsLayer: outputs[2,B,T,OUT] (loc, softplus-scale) + state_out[B,NS]
// Plan:
//   ck_* : fp32 -> f16 conversions / layout prep (x, Bm^T, [C|D]^T, A scan layout)
//   gemm<256,0>: U = x @ Bm + b            (f16 MFMA, out f16 in ws)
//   scan       : s_{t+1} = tanh(u_t + s_t A)  64 WGs (1/batch row), 512 thr.
//                A split: pairs 0..5 LDS-resident (96 KB, separate port),
//                pairs 6..17 areg (plain loads, compiler may hold or stream),
//                pairs 18..31 streamed from L2 (round-0 pipeline pattern).
//                NOTE rounds 2/3 failed identically with exotic register-pin
//                constructs (empty-asm "+v" tie / volatile loads); this round
//                is a strict superset of the VERIFIED round-0 code paths.
//   gemm<512,1>: loc = S@C + c ; scale = softplus(S@D + d)  (fp32 out)
// ---------------------------------------------------------------------------

typedef _Float16 f16;
typedef _Float16 f16x2 __attribute__((ext_vector_type(2)));
typedef _Float16 f16x4 __attribute__((ext_vector_type(4)));
typedef _Float16 f16x8 __attribute__((ext_vector_type(8)));
typedef float    f32x4 __attribute__((ext_vector_type(4)));

#define NS 512

// ws byte offsets (total ~129.3 MB). x16 shares the S16 region: x16 is dead
// after gemm1; scan then overwrites the region with S16.
#define OFF_S16   (0ull)            // 67,108,864   (S: [B*T, 512] f16)
#define OFF_X16   (0ull)            // 33,554,432   (x16 lives here during phase 1)
#define OFF_U16   (67108864ull)     // 67,108,864   (U: [B*T, 512] f16, bias added)
#define OFF_BMT   (134217728ull)    //    262,144   (Bm^T: [512][256] f16)
#define OFF_CDT   (134479872ull)    //    524,288   ([C|D]^T: [512][512] f16)
#define OFF_APREP (135004160ull)    //    196,608   (A areg-part, per-thread packed)
#define OFF_ALDS  (135200768ull)    //     98,304   (A LDS-part)
#define OFF_ASTR  (135299072ull)    //    229,376   (A streamed-part)

#if defined(__has_builtin)
#  if __has_builtin(__builtin_amdgcn_fdot2)
#    define HAS_FDOT2 1
#  endif
#endif

__device__ __forceinline__ float fdot2f(unsigned a, unsigned s, float c) {
#ifdef HAS_FDOT2
  return __builtin_amdgcn_fdot2(__builtin_bit_cast(f16x2, a),
                                __builtin_bit_cast(f16x2, s), c, false);
#else
  f16x2 av = __builtin_bit_cast(f16x2, a);
  f16x2 sv = __builtin_bit_cast(f16x2, s);
  return c + (float)av[0] * (float)sv[0] + (float)av[1] * (float)sv[1];
#endif
}

__device__ __forceinline__ unsigned packh2(float a, float b) {
  f16x2 h; h[0] = (f16)a; h[1] = (f16)b;
  return __builtin_bit_cast(unsigned, h);
}

// ------------------------------ prep kernels -------------------------------

__global__ void ck_x(const float* __restrict__ xg, f16* __restrict__ x16) {
  int i = (blockIdx.x * 256 + threadIdx.x) * 4;
  float4 v = *(const float4*)(xg + i);
  f16x4 h; h[0] = (f16)v.x; h[1] = (f16)v.y; h[2] = (f16)v.z; h[3] = (f16)v.w;
  *(f16x4*)(x16 + i) = h;
}

__global__ void ck_bmt(const float* __restrict__ Bm, f16* __restrict__ BmT) {
  int g = blockIdx.x * 256 + threadIdx.x;   // 131072 = 512*256
  int n = g >> 8, k = g & 255;
  BmT[g] = (f16)Bm[k * 512 + n];            // BmT[n][k]
}

__global__ void ck_cdt(const float* __restrict__ C, const float* __restrict__ D,
                       f16* __restrict__ CDT) {
  int g = blockIdx.x * 256 + threadIdx.x;   // 262144 = 512*512
  int n = g >> 9, k = g & 511;
  float v = (n < 256) ? C[k * 256 + n] : D[k * 256 + (n - 256)];
  CDT[g] = (f16)v;                          // CDT[n][k], n<256 -> C, else D
}

// A scan layout. Scan thread t: kb = t>>6 (k-block of 64 rows = 32 row-pairs),
// l = t&63; its 8 output columns are j = jj*64 + l (jj = 0..7).
// Pair p (local to kb) packs rows k0 = kb*64 + 2p, k0+1 at column j.
//  LDS part  (pairs 0..5):   quad F = q*512 + t, q = pl*2 + jj2, pl = 0..5
//                            dword component d: jj = jj2*4 + d
//  areg part (pairs 6..17):  dword h = t*96 + P*8 + jj, P = p-6 (0..11)
//  STREAM    (pairs 18..31): quad F = f*512 + t, f = pp*2 + jj2, pp = p-18
//                            dword component d: jj = jj2*4 + d
__global__ void ck_a(const float* __restrict__ Ag, unsigned* __restrict__ Aprep,
                     unsigned* __restrict__ Alds, unsigned* __restrict__ Astr) {
  int g = blockIdx.x * 256 + threadIdx.x;   // 131072 packed dwords total
  if (g < 24576) {
    // LDS part: pairs 0..5 (6144 quads)
    int F = g >> 2, d = g & 3;
    int t = F & 511, q = F >> 9;            // q = 0..11
    int pl = q >> 1, jj2 = q & 1;
    int kb = t >> 6, l = t & 63;
    int jj = jj2 * 4 + d;
    int k0 = kb * 64 + 2 * pl;
    int j = jj * 64 + l;
    Alds[g] = packh2(Ag[k0 * 512 + j], Ag[(k0 + 1) * 512 + j]);
  } else if (g < 73728) {
    // areg part: pairs 6..17 (96 dwords per thread)
    int h = g - 24576;                      // 49152 dwords
    int t = h / 96, rr = h % 96;
    int P = rr >> 3, jj = rr & 7;
    int kb = t >> 6, l = t & 63;
    int k0 = kb * 64 + 12 + 2 * P;
    int j = jj * 64 + l;
    Aprep[h] = packh2(Ag[k0 * 512 + j], Ag[(k0 + 1) * 512 + j]);
  } else {
    // stream part: pairs 18..31 (14336 quads)
    int q2 = g - 73728;                     // 57344 dwords
    int F = q2 >> 2, d = q2 & 3;
    int t = F & 511, f = F >> 9;            // f = 0..27
    int pp = f >> 1, jj2 = f & 1;
    int kb = t >> 6, l = t & 63;
    int jj = jj2 * 4 + d;
    int k0 = kb * 64 + 36 + 2 * pp;
    int j = jj * 64 + l;
    Astr[q2] = packh2(Ag[k0 * 512 + j], Ag[(k0 + 1) * 512 + j]);
  }
}

// ------------------------------- GEMM --------------------------------------
// C[M,128-tile] = A[M,K] @ B  with B given transposed: Bt[n][k].
// Block 256 thr = 4 waves, each wave a 64x64 quadrant, 16x16x32 f16 MFMA.
// MODE 0: out f16 = val + bias0[n]   (U)
// MODE 1: n<256 -> loc = val + bias0[n] ; else scale = softplus(val + bias1[n-256])
template <int KDIM, int MODE>
__global__ __launch_bounds__(256, 2) void gemm_kernel(
    const f16* __restrict__ Ag, const f16* __restrict__ Bt,
    const float* __restrict__ bias0, const float* __restrict__ bias1,
    void* __restrict__ outp) {
  __shared__ f16 At[128 * 40];   // 32 k + 8 pad per row (bank-conflict-free b128)
  __shared__ f16 Bs[128 * 40];
  const int tid = threadIdx.x;
  const int m0 = blockIdx.y * 128;
  const int n0 = blockIdx.x * 128;
  const int w = tid >> 6, lane = tid & 63;
  const int wm = w & 1, wn = w >> 1;
  const int r = lane & 15, qd = lane >> 4;

  f32x4 zero4 = {0.f, 0.f, 0.f, 0.f};
  f32x4 acc[4][4];
#pragma unroll
  for (int mt = 0; mt < 4; ++mt)
#pragma unroll
    for (int nt = 0; nt < 4; ++nt) acc[mt][nt] = zero4;

  for (int kk = 0; kk < KDIM; kk += 32) {
#pragma unroll
    for (int s = 0; s < 2; ++s) {
      int fi = tid * 2 + s;
      int row = fi >> 2, q = fi & 3;
      float4 av = *(const float4*)(Ag + (size_t)(m0 + row) * KDIM + kk + q * 8);
      *(float4*)(At + row * 40 + q * 8) = av;
      float4 bv = *(const float4*)(Bt + (size_t)(n0 + row) * KDIM + kk + q * 8);
      *(float4*)(Bs + row * 40 + q * 8) = bv;
    }
    __syncthreads();
    f16x8 af[4], bf[4];
#pragma unroll
    for (int mt = 0; mt < 4; ++mt)
      af[mt] = *(const f16x8*)(At + (wm * 64 + mt * 16 + r) * 40 + qd * 8);
#pragma unroll
    for (int nt = 0; nt < 4; ++nt)
      bf[nt] = *(const f16x8*)(Bs + (wn * 64 + nt * 16 + r) * 40 + qd * 8);
#pragma unroll
    for (int mt = 0; mt < 4; ++mt)
#pragma unroll
      for (int nt = 0; nt < 4; ++nt)
        acc[mt][nt] = __builtin_amdgcn_mfma_f32_16x16x32_f16(af[mt], bf[nt],
                                                             acc[mt][nt], 0, 0, 0);
    __syncthreads();
  }

#pragma unroll
  for (int mt = 0; mt < 4; ++mt) {
#pragma unroll
    for (int nt = 0; nt < 4; ++nt) {
      int n = n0 + wn * 64 + nt * 16 + r;
#pragma unroll
      for (int i = 0; i < 4; ++i) {
        int m = m0 + wm * 64 + mt * 16 + qd * 4 + i;
        float v = acc[mt][nt][i];
        if (MODE == 0) {
          ((f16*)outp)[(size_t)m * NS + n] = (f16)(v + bias0[n]);
        } else {
          if (n < 256) {
            ((float*)outp)[(size_t)m * 256 + n] = v + bias0[n];
          } else {
            float z = v + bias1[n - 256];
            float sp = (z > 20.f) ? z : log1pf(__expf(z));
            ((float*)outp)[16777216ull + (size_t)m * 256 + (n - 256)] = sp;
          }
        }
      }
    }
  }
}

// ------------------------------- scan --------------------------------------

#define BCU(x) __builtin_bit_cast(unsigned, (x))

#define REGDOT(P, SC)                                   \
  do {                                                  \
    unsigned sb_ = BCU(SC);                             \
    float4 a0_ = areg[(P) * 2], a1_ = areg[(P) * 2 + 1];\
    acc0 = fdot2f(BCU(a0_.x), sb_, acc0);               \
    acc1 = fdot2f(BCU(a0_.y), sb_, acc1);               \
    acc2 = fdot2f(BCU(a0_.z), sb_, acc2);               \
    acc3 = fdot2f(BCU(a0_.w), sb_, acc3);               \
    acc4 = fdot2f(BCU(a1_.x), sb_, acc4);               \
    acc5 = fdot2f(BCU(a1_.y), sb_, acc5);               \
    acc6 = fdot2f(BCU(a1_.z), sb_, acc6);               \
    acc7 = fdot2f(BCU(a1_.w), sb_, acc7);               \
  } while (0)

#define GAPDOT(LO, HI, SC)                              \
  do {                                                  \
    unsigned sb_ = BCU(SC);                             \
    acc0 = fdot2f(BCU((LO).x), sb_, acc0);              \
    acc1 = fdot2f(BCU((LO).y), sb_, acc1);              \
    acc2 = fdot2f(BCU((LO).z), sb_, acc2);              \
    acc3 = fdot2f(BCU((LO).w), sb_, acc3);              \
    acc4 = fdot2f(BCU((HI).x), sb_, acc4);              \
    acc5 = fdot2f(BCU((HI).y), sb_, acc5);              \
    acc6 = fdot2f(BCU((HI).z), sb_, acc6);              \
    acc7 = fdot2f(BCU((HI).w), sb_, acc7);              \
  } while (0)

__global__ __launch_bounds__(512, 2) void scan_kernel(
    const float4* __restrict__ Aprep4, const float4* __restrict__ Alds4,
    const float4* __restrict__ Astr4, const f16* __restrict__ U16,
    f16* __restrict__ S16, float* __restrict__ stout) {
  __shared__ __align__(16) f16 ldsA[49152];          // A pairs 0..5, 96 KB
  __shared__ float part[4096];                       // [kb][j] partials, 16 KB
  __shared__ __align__(16) f16 sh[512];              // state f16 (read as float4)
  const int t = threadIdx.x;
  const int b = blockIdx.x;
  const int kb = t >> 6;
  const int l = t & 63;

  // LDS A-part: thread t copies exactly the quads it will read (self-coherent)
  float4* ldsA4 = (float4*)ldsA;
#pragma unroll
  for (int q = 0; q < 12; ++q) ldsA4[q * 512 + t] = Alds4[q * 512 + t];

  // areg part (pairs 6..17): plain loads, round-0 code shape. If the compiler
  // holds them: 96 VGPRs of A never touch memory again. If it sinks them into
  // the loop: correct, just streamed (round-0 behavior).
  float4 areg[24];
#pragma unroll
  for (int i = 0; i < 24; ++i) areg[i] = Aprep4[t * 24 + i];

  sh[t] = (f16)0.f;                                  // s_0 = 0
  __syncthreads();

  const float4* sp4 = (const float4*)sh;
  float ns_prev = 0.f;

#pragma unroll 1
  for (int ts = 0; ts < 1024; ++ts) {
    // opaque zero: prevents LICM from hoisting the (loop-invariant) A-stream
    // loads out of the loop, which would blow the register budget
    int zoff;
    asm volatile("s_mov_b32 %0, 0" : "=s"(zoff));
    const float4* astr = Astr4 + zoff + t;

    const int row = b * 1024 + ts;
    // deferred store of last step's state: its vmcnt drain lands under this
    // step's long compute phase instead of right before barrier 2
    if (ts) S16[(size_t)(row - 1) * 512 + t] = (f16)ns_prev;
    f16 uh = U16[(size_t)row * 512 + t];             // u_t[j=t], issued early

    // stream batch 1 (pairs 18..21)
    float4 g0 = astr[0 * 512], g1 = astr[1 * 512];
    float4 g2 = astr[2 * 512], g3 = astr[3 * 512];
    float4 g4 = astr[4 * 512], g5 = astr[5 * 512];
    float4 g6 = astr[6 * 512], g7 = astr[7 * 512];

    float acc0 = 0.f, acc1 = 0.f, acc2 = 0.f, acc3 = 0.f;
    float acc4 = 0.f, acc5 = 0.f, acc6 = 0.f, acc7 = 0.f;

    // LDS part: pairs 0..3
    {
      float4 s4 = sp4[kb * 8 + 0];                   // wave-uniform broadcast
      float4 L0 = ldsA4[0 * 512 + t], L1 = ldsA4[1 * 512 + t];
      float4 L2 = ldsA4[2 * 512 + t], L3 = ldsA4[3 * 512 + t];
      float4 L4 = ldsA4[4 * 512 + t], L5 = ldsA4[5 * 512 + t];
      float4 L6 = ldsA4[6 * 512 + t], L7 = ldsA4[7 * 512 + t];
      GAPDOT(L0, L1, s4.x);
      GAPDOT(L2, L3, s4.y);
      GAPDOT(L4, L5, s4.z);
      GAPDOT(L6, L7, s4.w);
    }
    // LDS pairs 4,5 + areg pairs 6,7
    {
      float4 s4 = sp4[kb * 8 + 1];
      float4 L8 = ldsA4[8 * 512 + t],  L9  = ldsA4[9 * 512 + t];
      float4 L10 = ldsA4[10 * 512 + t], L11 = ldsA4[11 * 512 + t];
      GAPDOT(L8, L9, s4.x);
      GAPDOT(L10, L11, s4.y);
      REGDOT(0, s4.z);
      REGDOT(1, s4.w);
    }

    // stream batch 2 (pairs 22..25), latency covered by the areg block
    float4 h0 = astr[8 * 512],  h1 = astr[9 * 512];
    float4 h2 = astr[10 * 512], h3 = astr[11 * 512];
    float4 h4 = astr[12 * 512], h5 = astr[13 * 512];
    float4 h6 = astr[14 * 512], h7 = astr[15 * 512];

    // areg pairs 8..15
    {
      float4 s4 = sp4[kb * 8 + 2];
      REGDOT(2, s4.x); REGDOT(3, s4.y); REGDOT(4, s4.z); REGDOT(5, s4.w);
    }
    {
      float4 s4 = sp4[kb * 8 + 3];
      REGDOT(6, s4.x); REGDOT(7, s4.y); REGDOT(8, s4.z); REGDOT(9, s4.w);
    }
    // areg pairs 16,17 + streamed pairs 18,19
    {
      float4 s4 = sp4[kb * 8 + 4];
      REGDOT(10, s4.x); REGDOT(11, s4.y);
      GAPDOT(g0, g1, s4.z);
      GAPDOT(g2, g3, s4.w);
    }
    // streamed pairs 20..23; issue batch 3 (pairs 26..29) mid-block
    {
      float4 s4 = sp4[kb * 8 + 5];
      GAPDOT(g4, g5, s4.x);
      GAPDOT(g6, g7, s4.y);
      g0 = astr[16 * 512]; g1 = astr[17 * 512];
      g2 = astr[18 * 512]; g3 = astr[19 * 512];
      g4 = astr[20 * 512]; g5 = astr[21 * 512];
      g6 = astr[22 * 512]; g7 = astr[23 * 512];
      GAPDOT(h0, h1, s4.z);
      GAPDOT(h2, h3, s4.w);
    }
    // streamed pairs 24..27; issue batch 4 (pairs 30,31) mid-block
    {
      float4 s4 = sp4[kb * 8 + 6];
      GAPDOT(h4, h5, s4.x);
      GAPDOT(h6, h7, s4.y);
      h0 = astr[24 * 512]; h1 = astr[25 * 512];
      h2 = astr[26 * 512]; h3 = astr[27 * 512];
      GAPDOT(g0, g1, s4.z);
      GAPDOT(g2, g3, s4.w);
    }
    // streamed pairs 28..31
    {
      float4 s4 = sp4[kb * 8 + 7];
      GAPDOT(g4, g5, s4.x);
      GAPDOT(g6, g7, s4.y);
      GAPDOT(h0, h1, s4.z);
      GAPDOT(h2, h3, s4.w);
    }

    // partials: [kb][j], j = jj*64 + l -> lanes write consecutive dwords
    part[kb * 512 + 0 * 64 + l] = acc0;
    part[kb * 512 + 1 * 64 + l] = acc1;
    part[kb * 512 + 2 * 64 + l] = acc2;
    part[kb * 512 + 3 * 64 + l] = acc3;
    part[kb * 512 + 4 * 64 + l] = acc4;
    part[kb * 512 + 5 * 64 + l] = acc5;
    part[kb * 512 + 6 * 64 + l] = acc6;
    part[kb * 512 + 7 * 64 + l] = acc7;
    __syncthreads();

    // reduce over k-blocks for column j = t, add u, tanh
    float sum = (float)uh;
#pragma unroll
    for (int k2 = 0; k2 < 8; ++k2) sum += part[k2 * 512 + t];
    float e = __expf(2.f * sum);
    float ns = 1.f - 2.f / (e + 1.f);                // tanh(sum)

    sh[t] = (f16)ns;                                 // direct b16 write (2/bank = free)
    ns_prev = ns;
    if (ts == 1022) stout[b * 512 + t] = ns;         // prev_states[-1] = s_{1023}
    __syncthreads();
  }

  S16[(size_t)(b * 1024 + 1023) * 512 + t] = (f16)ns_prev;
}

// ------------------------------ launcher -----------------------------------

extern "C" void kernel_launch(void* const* d_in, const int* in_sizes, int n_in,
                              void* d_out, int out_size, void* d_ws, size_t ws_size,
                              hipStream_t stream) {
  (void)in_sizes; (void)n_in; (void)out_size; (void)ws_size;
  const float* xg  = (const float*)d_in[0];
  const float* Ag  = (const float*)d_in[1];
  const float* Bmg = (const float*)d_in[2];
  const float* bg  = (const float*)d_in[3];
  const float* Cg  = (const float*)d_in[4];
  const float* cg  = (const float*)d_in[5];
  const float* Dg  = (const float*)d_in[6];
  const float* dg  = (const float*)d_in[7];

  char* w = (char*)d_ws;
  f16* x16 = (f16*)(w + OFF_X16);
  f16* U16 = (f16*)(w + OFF_U16);
  f16* S16 = (f16*)(w + OFF_S16);
  f16* BmT = (f16*)(w + OFF_BMT);
  f16* CDT = (f16*)(w + OFF_CDT);
  unsigned* Aprep = (unsigned*)(w + OFF_APREP);
  unsigned* Alds  = (unsigned*)(w + OFF_ALDS);
  unsigned* Astr  = (unsigned*)(w + OFF_ASTR);
  float* out = (float*)d_out;

  ck_x  <<<16384, 256, 0, stream>>>(xg, x16);
  ck_bmt<<<  512, 256, 0, stream>>>(Bmg, BmT);
  ck_cdt<<< 1024, 256, 0, stream>>>(Cg, Dg, CDT);
  ck_a  <<<  512, 256, 0, stream>>>(Ag, Aprep, Alds, Astr);

  // U = x @ Bm + b
  gemm_kernel<256, 0><<<dim3(4, 512), 256, 0, stream>>>(x16, BmT, bg, nullptr,
                                                        (void*)U16);
  // sequential scan (overwrites x16 region with S16)
  scan_kernel<<<64, 512, 0, stream>>>((const float4*)Aprep, (const float4*)Alds,
                                      (const float4*)Astr, U16, S16,
                                      out + 33554432);
  // loc / softplus(scale) from S
  gemm_kernel<512, 1><<<dim3(4, 512), 256, 0, stream>>>(S16, CDT, cg, dg,
                                                        (void*)out);
}